// Round 1
// baseline (102.180 us; speedup 1.0000x reference)
//
#include <hip/hip_runtime.h>
#include <stdint.h>
#include <math.h>

#define BB 4
#define LL 12
#define NN 512
#define DMM 64
#define HH 8
#define DD 8
#define SK 35
#define IDX_TOTAL (NN*SK)   // 17920

// ---------------------------------------------------------------------------
// Threefry-2x32 (JAX-exact: 20 rounds, rotations {13,15,26,6}/{17,29,16,24})
// ---------------------------------------------------------------------------
__device__ __forceinline__ void tf2x32(uint32_t k0, uint32_t k1, uint32_t x0, uint32_t x1,
                                       uint32_t& o0, uint32_t& o1) {
  const uint32_t ks2 = k0 ^ k1 ^ 0x1BD11BDAu;
  uint32_t a = x0 + k0, b = x1 + k1;
#define TF_R(r) { a += b; b = (b << (r)) | (b >> (32 - (r))); b ^= a; }
  TF_R(13) TF_R(15) TF_R(26) TF_R(6)
  a += k1;  b += ks2 + 1u;
  TF_R(17) TF_R(29) TF_R(16) TF_R(24)
  a += ks2; b += k0 + 2u;
  TF_R(13) TF_R(15) TF_R(26) TF_R(6)
  a += k0;  b += k1 + 3u;
  TF_R(17) TF_R(29) TF_R(16) TF_R(24)
  a += k1;  b += ks2 + 4u;
  TF_R(13) TF_R(15) TF_R(26) TF_R(6)
  a += ks2; b += k0 + 5u;
#undef TF_R
  o0 = a; o1 = b;
}

// idx = jax.random.randint(key(42), (512,35), 0, 512)
// key(42) = (0,42). Partitionable (JAX>=0.5 default):
//   split foldlike: k2 = tf(key; 0, 1)  (full output pair)
//   random_bits(32): bits1 ^ bits2 of tf(k2; 0, i)
//   span=512 pow2 -> idx = bits & 511
__global__ __launch_bounds__(256) void idx_kernel(int* __restrict__ idx) {
  int i = blockIdx.x * 256 + threadIdx.x;
  if (i >= IDX_TOTAL) return;
  uint32_t ka, kb;
  tf2x32(0u, 42u, 0u, 1u, ka, kb);
  uint32_t b1, b2;
  tf2x32(ka, kb, 0u, (uint32_t)i, b1, b2);
  idx[i] = (int)((b1 ^ b2) & (uint32_t)(NN - 1));
}

// ---------------------------------------------------------------------------
// K1: projections. X:(B,L,N,64) @ W:(64,64) + b  ->  O layout [b][h][l][n][d]
// 128 rows/block, 256 threads, each thread: 4 rows x 8 cols register tile.
// ---------------------------------------------------------------------------
__global__ __launch_bounds__(256) void proj_kernel(
    const float* __restrict__ Xq, const float* __restrict__ Xk, const float* __restrict__ Xv,
    const float* __restrict__ Wq_, const float* __restrict__ Wk_, const float* __restrict__ Wv_,
    const float* __restrict__ bq_, const float* __restrict__ bk_, const float* __restrict__ bv_,
    float* __restrict__ Oq, float* __restrict__ Ok, float* __restrict__ Ov) {
  const int tz = blockIdx.y;
  const float* X    = (tz == 0) ? Xq  : (tz == 1) ? Xk  : Xv;
  const float* W    = (tz == 0) ? Wq_ : (tz == 1) ? Wk_ : Wv_;
  const float* bias = (tz == 0) ? bq_ : (tz == 1) ? bk_ : bv_;
  float* O          = (tz == 0) ? Oq  : (tz == 1) ? Ok  : Ov;

  __shared__ __align__(16) float Ws[64][64];
  __shared__ __align__(16) float Xs[128][68];   // pad 68: 16B-aligned rows, conflict-free col reads
  __shared__ float bs[64];

  const int tid = threadIdx.x;
  for (int i = tid; i < 1024; i += 256)
    ((float4*)Ws)[i] = ((const float4*)W)[i];
  if (tid < 64) bs[tid] = bias[tid];
  const size_t rowBase = (size_t)blockIdx.x * 128;
  const float* Xb = X + rowBase * 64;
  for (int i = tid; i < 2048; i += 256) {
    int r = i >> 4, c = (i & 15) << 2;
    *(float4*)&Xs[r][c] = ((const float4*)Xb)[i];
  }
  __syncthreads();

  const int hcol = tid & 7;   // head
  const int rb   = tid >> 3;  // 0..31
  float4 bv0 = *(float4*)&bs[hcol*8];
  float4 bv1 = *(float4*)&bs[hcol*8+4];
  float acc[4][8];
  #pragma unroll
  for (int i = 0; i < 4; ++i) {
    acc[i][0]=bv0.x; acc[i][1]=bv0.y; acc[i][2]=bv0.z; acc[i][3]=bv0.w;
    acc[i][4]=bv1.x; acc[i][5]=bv1.y; acc[i][6]=bv1.z; acc[i][7]=bv1.w;
  }
  #pragma unroll 4
  for (int m = 0; m < 64; ++m) {
    float4 w0 = *(const float4*)&Ws[m][hcol*8];
    float4 w1 = *(const float4*)&Ws[m][hcol*8+4];
    #pragma unroll
    for (int i = 0; i < 4; ++i) {
      float x = Xs[rb + 32*i][m];
      acc[i][0] = fmaf(x, w0.x, acc[i][0]);
      acc[i][1] = fmaf(x, w0.y, acc[i][1]);
      acc[i][2] = fmaf(x, w0.z, acc[i][2]);
      acc[i][3] = fmaf(x, w0.w, acc[i][3]);
      acc[i][4] = fmaf(x, w1.x, acc[i][4]);
      acc[i][5] = fmaf(x, w1.y, acc[i][5]);
      acc[i][6] = fmaf(x, w1.z, acc[i][6]);
      acc[i][7] = fmaf(x, w1.w, acc[i][7]);
    }
  }
  #pragma unroll
  for (int i = 0; i < 4; ++i) {
    size_t R = rowBase + rb + 32*i;
    int bI = (int)(R / (LL*NN));
    int lI = (int)((R / NN) % LL);
    int nI = (int)(R % NN);
    size_t off = ((((size_t)bI*HH + hcol)*LL + lI)*NN + nI)*DD;
    *(float4*)&O[off]     = make_float4(acc[i][0],acc[i][1],acc[i][2],acc[i][3]);
    *(float4*)&O[off + 4] = make_float4(acc[i][4],acc[i][5],acc[i][6],acc[i][7]);
  }
}

// ---------------------------------------------------------------------------
// K2: per-(b,h,l) sampled attention. LDS slabs transposed [8][512].
// ---------------------------------------------------------------------------
__global__ __launch_bounds__(256) void attn_kernel(
    const float* __restrict__ Qt, const float* __restrict__ Kt, const float* __restrict__ Vt,
    const int* __restrict__ gidx, float* __restrict__ out) {
  const int bid = blockIdx.x;          // ((b*H + h)*L + l)
  const int l = bid % LL;
  const int h = (bid / LL) % HH;
  const int b = bid / (LL*HH);
  const int tid = threadIdx.x;

  __shared__ float QsT[8][512];
  __shared__ float KsT[8][512];
  __shared__ float VsT[8][512];
  __shared__ float Ms[512];
  __shared__ float red[256];
  __shared__ __align__(16) float attnRet[SK][8];
  __shared__ __align__(16) float vmean[8];
  __shared__ int topIdx[SK];
  __shared__ int sel[512];

  // Phase A: load slabs (coalesced float4), store transposed.
  const size_t slabOff = (size_t)bid * (NN*DD);
  const float4* qs = (const float4*)(Qt + slabOff);
  const float4* ks = (const float4*)(Kt + slabOff);
  const float4* vs = (const float4*)(Vt + slabOff);
  #pragma unroll
  for (int it = 0; it < 4; ++it) {
    int i = tid + it*256;
    int n = i >> 1, db = (i & 1) * 4;
    float4 fq = qs[i], fk = ks[i], fv = vs[i];
    QsT[db+0][n]=fq.x; QsT[db+1][n]=fq.y; QsT[db+2][n]=fq.z; QsT[db+3][n]=fq.w;
    KsT[db+0][n]=fk.x; KsT[db+1][n]=fk.y; KsT[db+2][n]=fk.z; KsT[db+3][n]=fk.w;
    VsT[db+0][n]=fv.x; VsT[db+1][n]=fv.y; VsT[db+2][n]=fv.z; VsT[db+3][n]=fv.w;
  }
  sel[tid] = -1; sel[tid + 256] = -1;
  __syncthreads();

  // vmean partials (d = tid>>5, 32 partial sums per d)
  {
    int d = tid >> 5, part = tid & 31;
    float s = 0.f;
    #pragma unroll
    for (int j = 0; j < 16; ++j) s += VsT[d][part + 32*j];
    red[tid] = s;
  }

  // Phase B: M[r] = max_s(qk) - sum_s(qk)/N over the 35 sampled keys
  #pragma unroll
  for (int rr = 0; rr < 2; ++rr) {
    int r = tid + rr*256;
    float q[8];
    #pragma unroll
    for (int d = 0; d < 8; ++d) q[d] = QsT[d][r];
    int jv[SK];
    #pragma unroll
    for (int s = 0; s < SK; ++s) jv[s] = gidx[r*SK + s];   // prefetch, pipelined
    float mx = -INFINITY, sm = 0.f;
    #pragma unroll
    for (int s = 0; s < SK; ++s) {
      int j = jv[s];
      float dot = 0.f;
      #pragma unroll
      for (int d = 0; d < 8; ++d) dot = fmaf(q[d], KsT[d][j], dot);
      mx = fmaxf(mx, dot);
      sm += dot;
    }
    Ms[r] = mx - sm * (1.0f/NN);
  }
  __syncthreads();

  // vmean finalize on wave1 (parallel with wave0's top-k)
  if (tid >= 64 && tid < 72) {
    int d = tid - 64;
    float s = 0.f;
    for (int i = 0; i < 32; ++i) s += red[d*32 + i];
    vmean[d] = s * (1.0f/NN);
  }

  // Phase C: exact stable top-35 (value desc, index asc), wave0 only,
  // mutation-free: admit only elements strictly below previous pick.
  if (tid < 64) {
    const int lane = tid;
    float mv[8];
    #pragma unroll
    for (int j = 0; j < 8; ++j) mv[j] = Ms[lane + 64*j];
    float pv = INFINITY; int pi = -1;
    for (int t = 0; t < SK; ++t) {
      float bvv = -INFINITY; int bi = NN;
      #pragma unroll
      for (int j = 0; j < 8; ++j) {
        int r = lane + 64*j;
        float vv = mv[j];
        bool adm = (vv < pv) || (vv == pv && r > pi);
        if (adm && (vv > bvv || (vv == bvv && r < bi))) { bvv = vv; bi = r; }
      }
      #pragma unroll
      for (int off = 32; off >= 1; off >>= 1) {
        float ov = __shfl_xor(bvv, off);
        int   oi = __shfl_xor(bi, off);
        if (ov > bvv || (ov == bvv && oi < bi)) { bvv = ov; bi = oi; }
      }
      if (lane == 0) topIdx[t] = bi;
      pv = bvv; pi = bi;
    }
    if (lane < SK) sel[topIdx[lane]] = lane;
  }
  __syncthreads();

  // Phase D: full attention for the 35 selected query rows; wave w -> t = w, w+4, ...
  {
    const int wave = tid >> 6, lane = tid & 63;
    for (int t = wave; t < SK; t += 4) {
      const int row = topIdx[t];
      float q[8];
      #pragma unroll
      for (int d = 0; d < 8; ++d) q[d] = QsT[d][row];   // broadcast
      float p[8]; float mx = -INFINITY;
      #pragma unroll
      for (int j = 0; j < 8; ++j) {
        int n = lane + 64*j;
        float s = 0.f;
        #pragma unroll
        for (int d = 0; d < 8; ++d) s = fmaf(q[d], KsT[d][n], s);
        s *= 0.35355339059327373f;    // 1/sqrt(8)
        p[j] = s;
        mx = fmaxf(mx, s);
      }
      #pragma unroll
      for (int off = 32; off >= 1; off >>= 1) mx = fmaxf(mx, __shfl_xor(mx, off));
      float sum = 0.f;
      #pragma unroll
      for (int j = 0; j < 8; ++j) { p[j] = __expf(p[j] - mx); sum += p[j]; }
      #pragma unroll
      for (int off = 32; off >= 1; off >>= 1) sum += __shfl_xor(sum, off);
      float acc[8] = {0,0,0,0,0,0,0,0};
      #pragma unroll
      for (int j = 0; j < 8; ++j) {
        int n = lane + 64*j;
        float pj = p[j];
        #pragma unroll
        for (int d = 0; d < 8; ++d) acc[d] = fmaf(pj, VsT[d][n], acc[d]);
      }
      #pragma unroll
      for (int off = 32; off >= 1; off >>= 1) {
        #pragma unroll
        for (int d = 0; d < 8; ++d) acc[d] += __shfl_xor(acc[d], off);
      }
      if (lane == 0) {
        float inv = 1.0f / sum;
        #pragma unroll
        for (int d = 0; d < 8; ++d) attnRet[t][d] = acc[d] * inv;
      }
    }
  }
  __syncthreads();

  // Phase F: out[b][l][n][h*8 + c] = selected ? attnRet : vmean
  float* ob = out + ((size_t)(b*LL + l) * NN) * DMM + h*DD;
  #pragma unroll
  for (int it = 0; it < 4; ++it) {
    int i = tid + it*256;
    int n = i >> 1, hf = i & 1;
    int t = sel[n];
    float4 val = (t >= 0) ? *(const float4*)&attnRet[t][hf*4]
                          : *(const float4*)&vmean[hf*4];
    *(float4*)&ob[(size_t)n*DMM + hf*4] = val;
  }
}

// ---------------------------------------------------------------------------
extern "C" void kernel_launch(void* const* d_in, const int* in_sizes, int n_in,
                              void* d_out, int out_size, void* d_ws, size_t ws_size,
                              hipStream_t stream) {
  const float* q  = (const float*)d_in[0];
  const float* k  = (const float*)d_in[1];
  const float* v  = (const float*)d_in[2];
  const float* Wq = (const float*)d_in[3];
  const float* bq = (const float*)d_in[4];
  const float* Wk = (const float*)d_in[5];
  const float* bk = (const float*)d_in[6];
  const float* Wv = (const float*)d_in[7];
  const float* bv = (const float*)d_in[8];
  float* out = (float*)d_out;

  const size_t slab = (size_t)BB*HH*LL*NN*DD;   // 1,572,864 floats
  float* qT = (float*)d_ws;
  float* kT = qT + slab;
  float* vT = kT + slab;
  int* idx  = (int*)(vT + slab);                 // total ~18.1 MB of ws

  idx_kernel<<<IDX_TOTAL/256, 256, 0, stream>>>(idx);
  proj_kernel<<<dim3((BB*LL*NN)/128, 3), 256, 0, stream>>>(
      q, k, v, Wq, Wk, Wv, bq, bk, bv, qT, kT, vT);
  attn_kernel<<<BB*HH*LL, 256, 0, stream>>>(qT, kT, vT, idx, out);
}